// Round 13
// baseline (126.981 us; speedup 1.0000x reference)
//
#include <hip/hip_runtime.h>
#include <hip/hip_bf16.h>
#include <float.h>

// RigidityLoss: M=16384 gathered points, brute-force KNN (K=8) + loss.
// R12: transposed block decomposition. Block = 256 rows x 1024 cands
// (8 waves split ROWS; candidates shared -> staged once in 16 KB LDS,
// 8x less L2 traffic, broadcast ds_reads). 32x32x16 f16 MFMA (sq folded
// at k=3) with dv double-buffer (mfma(t+1) issued before unpack(t)) and
// 2-ahead LDS prefetch. Top-1 packed key per (row,cls) bin -> LDS
// bins[256][33]; in-block 16-lane extraction -> sorted top-8 per
// (row, split) -> keys[row][16][8] (8 MB, row-contiguous). Merge kernel:
// 32-lane group per row, lane holds 4 consecutive elems of one sorted
// list (exact), 8-round extraction + exact-f32 loss.

#define MPTS 16384
#define KNN  8
#define CDIM 16
#define LAMW 0.1f
#define EPSV 1e-6f

#define NSPLIT 16              // candidate splits (across blocks)
#define CSPL   1024            // candidates per split
#define NT     (CSPL/32)       // 32 MFMA tiles per wave
#define BROWS  256             // rows per block (8 waves x 32 rows)
#define BSTR   33              // padded bins row stride (words)

#define MED3 __builtin_amdgcn_fmed3f
typedef __attribute__((ext_vector_type(8)))  _Float16 f16x8;
typedef __attribute__((ext_vector_type(16))) float    f32x16;

__global__ __launch_bounds__(256) void k_gather(
    const float* __restrict__ canon, const float* __restrict__ trans,
    const int* __restrict__ indice, float4* __restrict__ c4,
    _Float16* __restrict__ bf16b, _Float16* __restrict__ af16b,
    float* __restrict__ acc)
{
    int t = blockIdx.x * 256 + threadIdx.x;
    if (t == 0) { acc[0] = 0.f; acc[1] = 0.f; }
    if (t < MPTS) {
        int j = indice[t];
        float x = canon[3*j+0] + trans[3*j+0];
        float y = canon[3*j+1] + trans[3*j+1];
        float z = canon[3*j+2] + trans[3*j+2];
        float sq = fmaf(x, x, fmaf(y, y, z*z));
        c4[t] = make_float4(-2.f*x, -2.f*y, -2.f*z, sq);   // exact f32 blob
        f16x8 aa = {};
        aa[0] = (_Float16)(-2.f*x); aa[1] = (_Float16)(-2.f*y);
        aa[2] = (_Float16)(-2.f*z); aa[3] = (_Float16)1.0f;
        *(f16x8*)(af16b + (size_t)t*8) = aa;
        f16x8 bb = {};
        bb[0] = (_Float16)x; bb[1] = (_Float16)y; bb[2] = (_Float16)z;
        bb[3] = (_Float16)sq;
        *(f16x8*)(bf16b + (size_t)t*8) = bb;
    }
}

__global__ __launch_bounds__(512, 4) void k_knn(
    const _Float16* __restrict__ bf16b, const _Float16* __restrict__ af16b,
    float* __restrict__ keys)
{
    __shared__ f16x8 shb[CSPL];              // 16 KB candidate chunk
    __shared__ float bins[BROWS * BSTR];     // 33.8 KB

    const int tid  = threadIdx.x;
    const int lane = tid & 63;
    const int wv   = tid >> 6;               // wave = row-subtile 0..7
    const int csplit  = blockIdx.x & (NSPLIT-1);
    const int rowbase = (blockIdx.x >> 4) * BROWS;
    const int cls  = lane & 31;
    const int cbeg = csplit * CSPL;

    // stage 1024 candidate blobs (shared by all 8 waves)
    shb[tid]       = *(const f16x8*)(bf16b + (size_t)(cbeg + tid) * 8);
    shb[tid + 512] = *(const f16x8*)(bf16b + (size_t)(cbeg + tid + 512) * 8);

    // A fragment: lane l<32 -> row (rowbase + wv*32 + l), k=0..7; upper zero.
    f16x8 afrag = *(const f16x8*)(af16b + (size_t)(rowbase + wv * 32 + cls) * 8);
    if (lane >= 32) { f16x8 zz = {}; afrag = zz; }
    f32x16 zero16 = {};

    const unsigned HMASK = 0xFFFFC000u;
    const unsigned ivb   = (unsigned)(cbeg + cls);

    // 16 row-states (g -> row (g&3)+8*(g>>2)+4*(lane>>5)), top-1 each
    float e0=FLT_MAX,e1=FLT_MAX,e2=FLT_MAX,e3=FLT_MAX;
    float e4=FLT_MAX,e5=FLT_MAX,e6=FLT_MAX,e7=FLT_MAX;
    float e8=FLT_MAX,e9=FLT_MAX,e10=FLT_MAX,e11=FLT_MAX;
    float e12=FLT_MAX,e13=FLT_MAX,e14=FLT_MAX,e15=FLT_MAX;

    __syncthreads();

#define UNPACK(DV, T)                                                          \
    {                                                                          \
        unsigned iv = ivb + (unsigned)((T) * 32);                              \
        float kf;                                                              \
        kf = __uint_as_float((__float_as_uint(DV[0])  & HMASK) | iv); e0  = fminf(e0,  kf); \
        kf = __uint_as_float((__float_as_uint(DV[1])  & HMASK) | iv); e1  = fminf(e1,  kf); \
        kf = __uint_as_float((__float_as_uint(DV[2])  & HMASK) | iv); e2  = fminf(e2,  kf); \
        kf = __uint_as_float((__float_as_uint(DV[3])  & HMASK) | iv); e3  = fminf(e3,  kf); \
        kf = __uint_as_float((__float_as_uint(DV[4])  & HMASK) | iv); e4  = fminf(e4,  kf); \
        kf = __uint_as_float((__float_as_uint(DV[5])  & HMASK) | iv); e5  = fminf(e5,  kf); \
        kf = __uint_as_float((__float_as_uint(DV[6])  & HMASK) | iv); e6  = fminf(e6,  kf); \
        kf = __uint_as_float((__float_as_uint(DV[7])  & HMASK) | iv); e7  = fminf(e7,  kf); \
        kf = __uint_as_float((__float_as_uint(DV[8])  & HMASK) | iv); e8  = fminf(e8,  kf); \
        kf = __uint_as_float((__float_as_uint(DV[9])  & HMASK) | iv); e9  = fminf(e9,  kf); \
        kf = __uint_as_float((__float_as_uint(DV[10]) & HMASK) | iv); e10 = fminf(e10, kf); \
        kf = __uint_as_float((__float_as_uint(DV[11]) & HMASK) | iv); e11 = fminf(e11, kf); \
        kf = __uint_as_float((__float_as_uint(DV[12]) & HMASK) | iv); e12 = fminf(e12, kf); \
        kf = __uint_as_float((__float_as_uint(DV[13]) & HMASK) | iv); e13 = fminf(e13, kf); \
        kf = __uint_as_float((__float_as_uint(DV[14]) & HMASK) | iv); e14 = fminf(e14, kf); \
        kf = __uint_as_float((__float_as_uint(DV[15]) & HMASK) | iv); e15 = fminf(e15, kf); \
    }

    // dv double-buffer + 2-ahead LDS prefetch: mfma(t+1) issues before
    // unpack(t); b for t+2 is already outstanding (counted lgkmcnt).
    f16x8 b1 = shb[cls + 32];
    f32x16 dvA = __builtin_amdgcn_mfma_f32_32x32x16_f16(shb[cls], b1, zero16, 0, 0, 0);
    // NOTE: the above B operand must be tile 0, not b1 -- fixed below.
    dvA = __builtin_amdgcn_mfma_f32_32x32x16_f16(afrag, shb[cls], zero16, 0, 0, 0);
    for (int t = 0; t < NT - 1; ++t) {
        f16x8 b2 = shb[((t + 2) & (NT - 1)) * 32 + cls];
        f32x16 dvB = __builtin_amdgcn_mfma_f32_32x32x16_f16(afrag, b1, zero16, 0, 0, 0);
        UNPACK(dvA, t)
        dvA = dvB;
        b1 = b2;
    }
    UNPACK(dvA, NT - 1)
#undef UNPACK

    // dump 16 bins to LDS: bins[wv*32 + rowmap][cls]
    {
        float* bb = &bins[(wv * 32 + (lane >> 5) * 4) * BSTR + cls];
#define ST(RO, EG) bb[(RO) * BSTR] = EG;
        ST(0,e0)   ST(1,e1)   ST(2,e2)   ST(3,e3)
        ST(8,e4)   ST(9,e5)   ST(10,e6)  ST(11,e7)
        ST(16,e8)  ST(17,e9)  ST(18,e10) ST(19,e11)
        ST(24,e12) ST(25,e13) ST(26,e14) ST(27,e15)
#undef ST
    }
    __syncthreads();

    // ---- extraction: 32 16-lane groups x 8 batches cover 256 rows ----
    const int grp = tid >> 4;                // 0..31
    const int lr  = tid & 15;
    for (int b = 0; b < 8; ++b) {
        const int rl = b * 32 + grp;         // row-local 0..255
        float g0 = bins[rl * BSTR + lr];
        float g1 = bins[rl * BSTR + lr + 16];
        float tmp = fminf(g0, g1); g1 = fmaxf(g0, g1); g0 = tmp;

        float kres = FLT_MAX;
        #pragma unroll
        for (int s = 0; s < KNN; ++s) {
            float m = g0;
            m = fminf(m, __shfl_xor(m, 1));
            m = fminf(m, __shfl_xor(m, 2));
            m = fminf(m, __shfl_xor(m, 4));
            m = fminf(m, __shfl_xor(m, 8));
            bool mine = (g0 == m);           // keys unique (idx in low bits)
            kres = (lr == s) ? m : kres;
            g0 = mine ? g1 : g0;
            g1 = mine ? FLT_MAX : g1;
        }
        if (lr < KNN)
            keys[((size_t)(rowbase + rl) * NSPLIT + csplit) * KNN + lr] = kres;
    }
}

__global__ __launch_bounds__(256) void k_merge_loss(
    const float4* __restrict__ c4, const float* __restrict__ keys,
    const int* __restrict__ indice, const float* __restrict__ motion,
    const float* __restrict__ fdc, float* __restrict__ acc)
{
    __shared__ float rS[4], rM[4];
    const int tid  = threadIdx.x;
    const int lane = tid & 63;
    const int wv   = tid >> 6;
    const int sub  = lane >> 5;              // row within wave: 0..1
    const int lp   = lane & 31;
    const int row  = blockIdx.x * 8 + wv * 2 + sub;

    // lane lp holds 4 CONSECUTIVE elements of one sorted 8-list -> sorted
    float4 kv = *(const float4*)(keys + (size_t)row * (NSPLIT * KNN) + lp * 4);
    float c0 = kv.x, c1 = kv.y, c2 = kv.z, c3 = kv.w;

    // exact 8-round extraction over the 32-lane group
    float kres = FLT_MAX;
    #pragma unroll
    for (int s = 0; s < KNN; ++s) {
        float m = c0;
        m = fminf(m, __shfl_xor(m, 1));
        m = fminf(m, __shfl_xor(m, 2));
        m = fminf(m, __shfl_xor(m, 4));
        m = fminf(m, __shfl_xor(m, 8));
        m = fminf(m, __shfl_xor(m, 16));
        bool mine = (c0 == m);               // keys unique
        kres = (lp == s) ? m : kres;
        c0 = mine ? c1 : c0;
        c1 = mine ? c2 : c1;
        c2 = mine ? c3 : c2;
        c3 = mine ? FLT_MAX : c3;
    }

    // ---- loss: lanes lp<8 handle neighbors 0..7 of this row ----
    float4 rc = c4[row];
    const float qx=-0.5f*rc.x, qy=-0.5f*rc.y, qz=-0.5f*rc.z, qq=rc.w;

    int jk = (int)(__float_as_uint(kres) & 0x3FFFu);
    float4 nc = c4[jk];
    float te  = fmaf(qx, nc.x, fmaf(qy, nc.y, fmaf(qz, nc.z, nc.w)));
    float d2k = qq + te;                     // exact squared distance

    float xn = (lp < KNN) ? -0.5f*nc.x : 0.f;
    float yn = (lp < KNN) ? -0.5f*nc.y : 0.f;
    float zn = (lp < KNN) ? -0.5f*nc.z : 0.f;
    float sx = xn, sy = yn, sz = zn;
    sx += __shfl_xor(sx, 1); sx += __shfl_xor(sx, 2); sx += __shfl_xor(sx, 4);
    sy += __shfl_xor(sy, 1); sy += __shfl_xor(sy, 2); sy += __shfl_xor(sy, 4);
    sz += __shfl_xor(sz, 1); sz += __shfl_xor(sz, 2); sz += __shfl_xor(sz, 4);

    float surf = 0.f, simv = 0.f;
    if (lp < KNN) {
        if (lp == 0) {
            float dx = qx - sx * 0.125f + EPSV;
            float dy = qy - sy * 0.125f + EPSV;
            float dz = qz - sz * 0.125f + EPSV;
            surf = sqrtf(fmaf(dx, dx, fmaf(dy, dy, dz * dz)));
        }
        int irow = indice[row];
        int inb  = indice[jk];
        float c0v = fdc[3*irow+0] - fdc[3*inb+0] + EPSV;
        float c1v = fdc[3*irow+1] - fdc[3*inb+1] + EPSV;
        float c2v = fdc[3*irow+2] - fdc[3*inb+2] + EPSV;
        float cd2 = fmaf(c0v, c0v, fmaf(c1v, c1v, c2v * c2v));
        float w = __expf(-LAMW * fmaf(d2k, d2k, cd2));   // dist_w * color_w

        const float4* mr4 = (const float4*)(motion + CDIM * irow);
        const float4* mn4 = (const float4*)(motion + CDIM * inb);
        float s = 0.f;
        #pragma unroll
        for (int c = 0; c < CDIM/4; ++c) {
            float4 A = mr4[c], B = mn4[c];
            float h0 = A.x-B.x+EPSV, h1 = A.y-B.y+EPSV;
            float h2 = A.z-B.z+EPSV, h3 = A.w-B.w+EPSV;
            s = fmaf(h0,h0, fmaf(h1,h1, fmaf(h2,h2, fmaf(h3,h3, s))));
        }
        simv = w * sqrtf(s);
    }

    // ---- wave + block reduction ----
    float aS = surf, aM = simv;
    #pragma unroll
    for (int m = 1; m <= 32; m <<= 1) {
        aS += __shfl_xor(aS, m);
        aM += __shfl_xor(aM, m);
    }
    if (lane == 0) { rS[wv] = aS; rM[wv] = aM; }
    __syncthreads();
    if (tid == 0) {
        float tS = 0.f, tM = 0.f;
        #pragma unroll
        for (int w2 = 0; w2 < 4; ++w2) { tS += rS[w2]; tM += rM[w2]; }
        atomicAdd(&acc[0], tS);
        atomicAdd(&acc[1], tM);
    }
}

__global__ void k_final(const float* __restrict__ acc, float* __restrict__ out)
{
    out[0] = acc[0] * (1.0f / MPTS) + acc[1] * (1.0f / (MPTS * KNN));
}

extern "C" void kernel_launch(void* const* d_in, const int* in_sizes, int n_in,
                              void* d_out, int out_size, void* d_ws, size_t ws_size,
                              hipStream_t stream)
{
    const float* canon  = (const float*)d_in[0];
    const float* trans  = (const float*)d_in[1];
    const float* motion = (const float*)d_in[2];
    const float* fdc    = (const float*)d_in[3];
    const int*   indice = (const int*)d_in[4];
    float* out = (float*)d_out;

    char* ws = (char*)d_ws;
    float*     acc   = (float*)ws;                          // @0
    float4*    c4    = (float4*)(ws + 4096);                // 256 KB
    _Float16*  af16b = (_Float16*)(ws + 4096 + 262144);     // 256 KB
    _Float16*  bf16b = (_Float16*)(ws + 4096 + 2*262144);   // 256 KB
    float*     keys  = (float*)(ws + 4096 + 3*262144);      // M*16*8*4 = 8 MB

    k_gather<<<MPTS/256, 256, 0, stream>>>(canon, trans, indice, c4, bf16b, af16b, acc);
    k_knn<<<(MPTS/BROWS)*NSPLIT, 512, 0, stream>>>(bf16b, af16b, keys);
    k_merge_loss<<<MPTS/8, 256, 0, stream>>>(c4, keys, indice, motion, fdc, acc);
    k_final<<<1, 1, 0, stream>>>(acc, out);
}

// Round 14
// 39.542 us; speedup vs baseline: 3.2113x; 3.2113x over previous
//
#include <hip/hip_runtime.h>
#include <hip/hip_bf16.h>
#include <float.h>

// RigidityLoss: M=16384 gathered points, brute-force KNN (K=8) + loss.
// R13: exact R11 structure (MFMA distance via 32x32x16 f16 with sq folded
// at k=3, LDS bins, candidate-half split, exact two-pointer merge, 4-deep
// register prefetch ring at __launch_bounds__(512,4)), with the tile loop
// FULLY UNROLLED: straight-line code lets the scheduler hoist independent
// MFMAs over UNPACKs (covers MFMA latency + MAI-hazard padding with useful
// VALU) instead of serializing per tile across the loop back-edge.

#define MPTS 16384
#define KNN  8
#define CDIM 16
#define LAMW 0.1f
#define EPSV 1e-6f

#define ROWS   32              // rows per block (one 32x32 MFMA row-tile)
#define NSPLIT 8               // waves per block = candidate splits
#define CSPL   1024            // candidates per split (half / 8 waves)
#define NT     (CSPL/32)       // 32 MFMA tiles per wave
#define BSTR   257             // padded LDS bin-row stride (words)

#define MED3 __builtin_amdgcn_fmed3f
typedef __attribute__((ext_vector_type(8)))  _Float16 f16x8;
typedef __attribute__((ext_vector_type(16))) float    f32x16;

__global__ __launch_bounds__(256) void k_gather(
    const float* __restrict__ canon, const float* __restrict__ trans,
    const int* __restrict__ indice, float4* __restrict__ c4,
    _Float16* __restrict__ bf16b, _Float16* __restrict__ af16b,
    float* __restrict__ acc)
{
    int t = blockIdx.x * 256 + threadIdx.x;
    if (t == 0) { acc[0] = 0.f; acc[1] = 0.f; }
    if (t < MPTS) {
        int j = indice[t];
        float x = canon[3*j+0] + trans[3*j+0];
        float y = canon[3*j+1] + trans[3*j+1];
        float z = canon[3*j+2] + trans[3*j+2];
        float sq = fmaf(x, x, fmaf(y, y, z*z));
        c4[t] = make_float4(-2.f*x, -2.f*y, -2.f*z, sq);   // exact f32 blob
        f16x8 aa = {};
        aa[0] = (_Float16)(-2.f*x); aa[1] = (_Float16)(-2.f*y);
        aa[2] = (_Float16)(-2.f*z); aa[3] = (_Float16)1.0f;
        *(f16x8*)(af16b + (size_t)t*8) = aa;
        f16x8 bb = {};
        bb[0] = (_Float16)x; bb[1] = (_Float16)y; bb[2] = (_Float16)z;
        bb[3] = (_Float16)sq;
        *(f16x8*)(bf16b + (size_t)t*8) = bb;
    }
}

__global__ __launch_bounds__(512, 4) void k_knn(
    const _Float16* __restrict__ bf16b, const _Float16* __restrict__ af16b,
    float* __restrict__ keys)
{
    __shared__ float bins[ROWS * BSTR];      // 32.9 KB

    const int tid  = threadIdx.x;
    const int lane = tid & 63;
    const int wv   = tid >> 6;               // wave = candidate split 0..7
    const int half = blockIdx.x & 1;
    const int rowbase = (blockIdx.x >> 1) * ROWS;
    const int cls  = lane & 31;
    const int cbeg = half * (MPTS/2) + wv * CSPL;

    // A fragment: lane l<32 -> row (rowbase+l), k=0..7; lanes>=32 (k=8..15) zero.
    f16x8 afrag = *(const f16x8*)(af16b + (size_t)(rowbase + cls) * 8);
    if (lane >= 32) { f16x8 zz = {}; afrag = zz; }
    f32x16 zero16 = {};

    const _Float16* bptr  = bf16b + (size_t)(cbeg + cls) * 8;
    const unsigned  HMASK = 0xFFFFC000u;
    const unsigned  ivb   = (unsigned)(cbeg + cls);

    // 16 row-states (g -> row (g&3)+8*(g>>2)+4*(lane>>5)), top-1 each
    float e0=FLT_MAX,e1=FLT_MAX,e2=FLT_MAX,e3=FLT_MAX;
    float e4=FLT_MAX,e5=FLT_MAX,e6=FLT_MAX,e7=FLT_MAX;
    float e8=FLT_MAX,e9=FLT_MAX,e10=FLT_MAX,e11=FLT_MAX;
    float e12=FLT_MAX,e13=FLT_MAX,e14=FLT_MAX,e15=FLT_MAX;

#define LD(T) (*(const f16x8*)(bptr + (size_t)(((T) & (NT-1)) * 256)))
#define DOTILE(PB, T)                                                          \
    {                                                                          \
        f32x16 dv = __builtin_amdgcn_mfma_f32_32x32x16_f16(afrag, PB, zero16, 0, 0, 0); \
        unsigned iv = ivb + (unsigned)((T) * 32);                              \
        float kf;                                                              \
        kf = __uint_as_float((__float_as_uint(dv[0])  & HMASK) | iv); e0  = fminf(e0,  kf); \
        kf = __uint_as_float((__float_as_uint(dv[1])  & HMASK) | iv); e1  = fminf(e1,  kf); \
        kf = __uint_as_float((__float_as_uint(dv[2])  & HMASK) | iv); e2  = fminf(e2,  kf); \
        kf = __uint_as_float((__float_as_uint(dv[3])  & HMASK) | iv); e3  = fminf(e3,  kf); \
        kf = __uint_as_float((__float_as_uint(dv[4])  & HMASK) | iv); e4  = fminf(e4,  kf); \
        kf = __uint_as_float((__float_as_uint(dv[5])  & HMASK) | iv); e5  = fminf(e5,  kf); \
        kf = __uint_as_float((__float_as_uint(dv[6])  & HMASK) | iv); e6  = fminf(e6,  kf); \
        kf = __uint_as_float((__float_as_uint(dv[7])  & HMASK) | iv); e7  = fminf(e7,  kf); \
        kf = __uint_as_float((__float_as_uint(dv[8])  & HMASK) | iv); e8  = fminf(e8,  kf); \
        kf = __uint_as_float((__float_as_uint(dv[9])  & HMASK) | iv); e9  = fminf(e9,  kf); \
        kf = __uint_as_float((__float_as_uint(dv[10]) & HMASK) | iv); e10 = fminf(e10, kf); \
        kf = __uint_as_float((__float_as_uint(dv[11]) & HMASK) | iv); e11 = fminf(e11, kf); \
        kf = __uint_as_float((__float_as_uint(dv[12]) & HMASK) | iv); e12 = fminf(e12, kf); \
        kf = __uint_as_float((__float_as_uint(dv[13]) & HMASK) | iv); e13 = fminf(e13, kf); \
        kf = __uint_as_float((__float_as_uint(dv[14]) & HMASK) | iv); e14 = fminf(e14, kf); \
        kf = __uint_as_float((__float_as_uint(dv[15]) & HMASK) | iv); e15 = fminf(e15, kf); \
    }

    // 4-deep static ring prefetch, FULL UNROLL: all LD/MFMA/UNPACK indices
    // static -> scheduler interleaves MFMAs ahead of UNPACKs freely.
    f16x8 p0 = LD(0), p1 = LD(1), p2 = LD(2), p3 = LD(3);
    #pragma unroll
    for (int t = 0; t < NT; t += 4) {
        f16x8 n0 = LD(t+4), n1 = LD(t+5);
        DOTILE(p0, t+0)
        DOTILE(p1, t+1)
        f16x8 n2 = LD(t+6), n3 = LD(t+7);
        DOTILE(p2, t+2)
        DOTILE(p3, t+3)
        p0 = n0; p1 = n1; p2 = n2; p3 = n3;
    }
#undef DOTILE
#undef LD

    // dump 16 bins to LDS: bins[rowL][wv*32 + cls], rowL = ST-row + (lane>>5)*4
    {
        float* bb = &bins[((lane >> 5) * 4) * BSTR + wv * 32 + cls];
#define ST(RO, EG) bb[(RO) * BSTR] = EG;
        ST(0,e0)   ST(1,e1)   ST(2,e2)   ST(3,e3)
        ST(8,e4)   ST(9,e5)   ST(10,e6)  ST(11,e7)
        ST(16,e8)  ST(17,e9)  ST(18,e10) ST(19,e11)
        ST(24,e12) ST(25,e13) ST(26,e14) ST(27,e15)
#undef ST
    }
    __syncthreads();

    // ---- merge: wave wv owns rows 4wv..4wv+3; 16 lanes per row ----
    const int sr = lane >> 4;                // sub-row 0..3
    const int lr = lane & 15;                // lane within row group
    const int rl = wv * 4 + sr;              // row-local 0..31
    const int row = rowbase + rl;

    // per-lane top-2 over its 16 bins
    float g0 = FLT_MAX, g1 = FLT_MAX;
    #pragma unroll
    for (int i = 0; i < 16; ++i) {
        float v = bins[rl * BSTR + i * 16 + lr];
        g1 = MED3(g0, g1, v);
        g0 = fminf(g0, v);
    }

    // extract 8 smallest among the 16 lanes x top-2; lane s ends with s-th
    float kres = FLT_MAX;
    #pragma unroll
    for (int s = 0; s < KNN; ++s) {
        float m = g0;
        m = fminf(m, __shfl_xor(m, 1));
        m = fminf(m, __shfl_xor(m, 2));
        m = fminf(m, __shfl_xor(m, 4));
        m = fminf(m, __shfl_xor(m, 8));
        bool mine = (g0 == m);               // keys unique (idx in low bits)
        kres = (lr == s) ? m : kres;
        g0 = mine ? g1 : g0;
        g1 = mine ? FLT_MAX : g1;
    }

    if (lr < KNN)
        keys[((size_t)half * MPTS + row) * KNN + lr] = kres;   // sorted list
}

__global__ __launch_bounds__(128) void k_merge_loss(
    const float4* __restrict__ c4, const float* __restrict__ keys,
    const int* __restrict__ indice, const float* __restrict__ motion,
    const float* __restrict__ fdc, float* __restrict__ acc)
{
    __shared__ float rS[2], rM[2];
    const int tid  = threadIdx.x;
    const int lane = tid & 63;
    const int wv   = tid >> 6;
    const int row  = blockIdx.x * 128 + tid;

    // two sorted 8-lists (named regs; fully static)
    const float4* pa4 = (const float4*)(keys + (size_t)row * KNN);
    const float4* pb4 = (const float4*)(keys + ((size_t)MPTS + row) * KNN);
    float4 A0 = pa4[0], A1 = pa4[1], B0 = pb4[0], B1 = pb4[1];
    float a0=A0.x,a1=A0.y,a2=A0.z,a3=A0.w,a4=A1.x,a5=A1.y,a6=A1.z,a7=A1.w;
    float b0=B0.x,b1=B0.y,b2=B0.z,b3=B0.w,b4=B1.x,b5=B1.y,b6=B1.z,b7=B1.w;

    float4 rc = c4[row];
    const float qx=-0.5f*rc.x, qy=-0.5f*rc.y, qz=-0.5f*rc.z, qq=rc.w;
    const int irow = indice[row];
    const float f0 = fdc[3*irow+0], f1 = fdc[3*irow+1], f2 = fdc[3*irow+2];
    const float4* mr4 = (const float4*)(motion + CDIM * irow);
    float4 m0 = mr4[0], m1 = mr4[1], m2 = mr4[2], m3 = mr4[3];

    float sx = 0.f, sy = 0.f, sz = 0.f, simsum = 0.f;
    #pragma unroll
    for (int s = 0; s < KNN; ++s) {
        bool m = (a0 <= b0);
        float kk = m ? a0 : b0;
        // shift chosen list (all static-indexed)
        float na0=m?a1:a0, na1=m?a2:a1, na2=m?a3:a2, na3=m?a4:a3;
        float na4=m?a5:a4, na5=m?a6:a5, na6=m?a7:a6, na7=m?FLT_MAX:a7;
        float nb0=m?b0:b1, nb1=m?b1:b2, nb2=m?b2:b3, nb3=m?b3:b4;
        float nb4=m?b4:b5, nb5=m?b5:b6, nb6=m?b6:b7, nb7=m?b7:FLT_MAX;
        a0=na0;a1=na1;a2=na2;a3=na3;a4=na4;a5=na5;a6=na6;a7=na7;
        b0=nb0;b1=nb1;b2=nb2;b3=nb3;b4=nb4;b5=nb5;b6=nb6;b7=nb7;

        int jk = (int)(__float_as_uint(kk) & 0x3FFFu);
        float4 nc = c4[jk];
        // exact squared distance (same expanded form as reference)
        float te  = fmaf(qx, nc.x, fmaf(qy, nc.y, fmaf(qz, nc.z, nc.w)));
        float d2k = qq + te;
        sx += -0.5f*nc.x; sy += -0.5f*nc.y; sz += -0.5f*nc.z;

        int inb = indice[jk];
        float c0v = f0 - fdc[3*inb+0] + EPSV;
        float c1v = f1 - fdc[3*inb+1] + EPSV;
        float c2v = f2 - fdc[3*inb+2] + EPSV;
        float cd2 = fmaf(c0v, c0v, fmaf(c1v, c1v, c2v * c2v));
        float w = __expf(-LAMW * fmaf(d2k, d2k, cd2));  // dist_w * color_w fused

        const float4* mn4 = (const float4*)(motion + CDIM * inb);
        float4 u0 = mn4[0], u1 = mn4[1], u2 = mn4[2], u3 = mn4[3];
        float sacc = 0.f;
#define MD(A,B) { float g0v=A.x-B.x+EPSV, g1v=A.y-B.y+EPSV,               \
                        g2v=A.z-B.z+EPSV, g3v=A.w-B.w+EPSV;               \
                  sacc = fmaf(g0v,g0v,fmaf(g1v,g1v,fmaf(g2v,g2v,fmaf(g3v,g3v,sacc)))); }
        MD(m0,u0) MD(m1,u1) MD(m2,u2) MD(m3,u3)
#undef MD
        simsum += w * sqrtf(sacc);
    }

    float dx = qx - sx * 0.125f + EPSV;
    float dy = qy - sy * 0.125f + EPSV;
    float dz = qz - sz * 0.125f + EPSV;
    float surf = sqrtf(fmaf(dx, dx, fmaf(dy, dy, dz * dz)));

    // ---- block reduction ----
    float aS = surf, aM = simsum;
    #pragma unroll
    for (int m = 1; m <= 32; m <<= 1) {
        aS += __shfl_xor(aS, m);
        aM += __shfl_xor(aM, m);
    }
    if (lane == 0) { rS[wv] = aS; rM[wv] = aM; }
    __syncthreads();
    if (tid == 0) {
        float tS = rS[0] + rS[1], tM = rM[0] + rM[1];
        atomicAdd(&acc[0], tS);
        atomicAdd(&acc[1], tM);
    }
}

__global__ void k_final(const float* __restrict__ acc, float* __restrict__ out)
{
    out[0] = acc[0] * (1.0f / MPTS) + acc[1] * (1.0f / (MPTS * KNN));
}

extern "C" void kernel_launch(void* const* d_in, const int* in_sizes, int n_in,
                              void* d_out, int out_size, void* d_ws, size_t ws_size,
                              hipStream_t stream)
{
    const float* canon  = (const float*)d_in[0];
    const float* trans  = (const float*)d_in[1];
    const float* motion = (const float*)d_in[2];
    const float* fdc    = (const float*)d_in[3];
    const int*   indice = (const int*)d_in[4];
    float* out = (float*)d_out;

    char* ws = (char*)d_ws;
    float*     acc   = (float*)ws;                          // @0
    float4*    c4    = (float4*)(ws + 4096);                // 256 KB
    _Float16*  af16b = (_Float16*)(ws + 4096 + 262144);     // 256 KB
    _Float16*  bf16b = (_Float16*)(ws + 4096 + 2*262144);   // 256 KB
    float*     keys  = (float*)(ws + 4096 + 3*262144);      // 2*M*8*4 = 1 MB

    k_gather<<<MPTS/256, 256, 0, stream>>>(canon, trans, indice, c4, bf16b, af16b, acc);
    k_knn<<<(MPTS/ROWS)*2, 512, 0, stream>>>(bf16b, af16b, keys);
    k_merge_loss<<<MPTS/128, 128, 0, stream>>>(c4, keys, indice, motion, fdc, acc);
    k_final<<<1, 1, 0, stream>>>(acc, out);
}